// Round 13
// baseline (75.829 us; speedup 1.0000x reference)
//
#include <hip/hip_runtime.h>
#include <hip/hip_bf16.h>
#include <math.h>

// NVAR reservoir: out = GELU(poly_feats(x) @ W1 + b1) @ W2 + b2
// B=2 S=512 E=64 DELAY=5 -> L=320, F=51681, tokens=1024
//
// R13: R12's rolled control structure + R8's precomputed swizzled A-image
// and fragment-ordered DC (kills the 16-way xw bank conflict found by desk
// check: A-build addr == j + t (mod 32), j = 8*lane+r -> 4 banks/64 lanes)
// + triangular kc-skip (B upper-tri: wave needs kc >= (3*wn)>>1; steps
// 11,10,8,7,5,4,2,1 balanced across SIMDs via wn-permutation) + k_pack
// skips never-read below-diagonal records.

#define NF     51681
#define KPAD   352
#define KCHK   11              // 352/32
#define NFR    24              // 384/16 (frags 21..23 zero)
#define NPAD   (NFR * 16)      // 384
#define MT2    128
#define ATS    768             // At row stride BYTES (multiple of 128)

typedef __attribute__((ext_vector_type(8))) short short8;
typedef __attribute__((ext_vector_type(4))) float f32x4;

#define W1C_BYTES  ((size_t)64 * NF * 2)                // 6,615,168
#define MF_BYTES   ((size_t)64 * KPAD * NPAD * 2)       // 17,301,504
#define HBUF_OFF   (W1C_BYTES + MF_BYTES)
#define AIMG_OFF   (HBUF_OFF + (size_t)1024 * 64 * 4)
#define AIMG_SH_PER_TILE 49152                          // 128 rows * 384 shorts
#define DC_OFF     (AIMG_OFF + (size_t)8 * AIMG_SH_PER_TILE * 2)
#define DC_SH_PER_TILE 49152                            // 768 recs * 64 lanes

__device__ __forceinline__ unsigned short f2bf(float x) {
    return __bfloat16_as_ushort(__float2bfloat16(x));
}
__device__ __forceinline__ float bf2f(unsigned short h) {
    union { unsigned u; float f; } v; v.u = ((unsigned)h) << 16; return v.f;
}

// ---- k_t: W1c[e][f] = bf16(W1[f][e]) ----
__global__ void k_t(const float* __restrict__ W1, unsigned short* __restrict__ W1c) {
    __shared__ float t[64 * 65];
    const int tid = threadIdx.x;
    const int f0 = blockIdx.x * 64;
    #pragma unroll 1
    for (int r = 0; r < 16; ++r) {
        int idx = r * 256 + tid;
        int fi = idx >> 6, e = idx & 63;
        t[fi * 65 + e] = (f0 + fi < NF) ? W1[(size_t)(f0 + fi) * 64 + e] : 0.f;
    }
    __syncthreads();
    #pragma unroll 1
    for (int r = 0; r < 16; ++r) {
        int idx = r * 256 + tid;
        int e = idx >> 6, fi = idx & 63;
        if (f0 + fi < NF)
            W1c[(size_t)e * NF + f0 + fi] = f2bf(t[fi * 65 + e]);
    }
}

// ---- k_pack: upper-triangular M'_e, fragment order; skip never-read recs ----
// short index = (((e*11 + kc)*24 + nf)*64 + lane)*8 + r
// j = kc*32 + (lane>>4)*8 + r, i = nf*16 + (lane&15)
__global__ void k_pack(const unsigned short* __restrict__ W1c,
                       unsigned short* __restrict__ Mfrag) {
    const int g = blockIdx.x * 256 + threadIdx.x;       // < 1,081,344
    const int lane = g & 63;
    const int rec = g >> 6;
    const int nf = rec % NFR;
    const int rec2 = rec / NFR;
    const int kc = rec2 % KCHK;
    const int e = rec2 / KCHK;

    // record read by k_main iff kc >= kc0 of the owning wave (wn = nf/3)
    const int kc0o = (3 * (nf / 3)) >> 1;
    if (kc < kc0o) return;                              // wave-uniform

    const int i = nf * 16 + (lane & 15);
    const int jb = kc * 32 + ((lane >> 4) << 3);
    const unsigned short* wrow = W1c + (size_t)e * NF;

    __attribute__((aligned(16))) unsigned short v[8];
    #pragma unroll
    for (int r = 0; r < 8; ++r) {
        int j = jb + r;
        unsigned short out = 0;
        if (i <= j && j <= 320) {
            if (j == 320) {
                out = (i == 320) ? wrow[0] : wrow[1 + i];
            } else {
                int idx = 321 + i * 320 - ((i * (i - 1)) >> 1) + (j - i);
                out = wrow[idx];
            }
        }
        v[r] = out;
    }
    *(short8*)(Mfrag + (size_t)g * 8) = *(short8*)v;
}

// ---- k_aprep: per-tile swizzled A-image + fragment-ordered contraction buf ----
// (R8-verified format; xwin stride 65 to spread banks)
__global__ void k_aprep(const float* __restrict__ x, unsigned short* __restrict__ Aimg,
                        unsigned short* __restrict__ DC) {
    __shared__ float xwin[132 * 65];
    const int tile = blockIdx.x >> 2;
    const int qtr  = blockIdx.x & 3;
    const int tid = threadIdx.x;
    const int b = tile >> 2, s0 = (tile & 3) * 128;

    #pragma unroll 1
    for (int idx = tid; idx < 132 * 64; idx += 256) {
        int r = idx >> 6, ee = idx & 63;
        int s = s0 - 4 + r;
        xwin[r * 65 + ee] = (s >= 0) ? x[((b << 9) + s) * 64 + ee] : 0.f;
    }
    __syncthreads();

    // A image: Aimg[tile][t*384 + s16/2 ..] = bf16 d'[t][j0..j0+7],
    // j0 = (s16 ^ ((t&7)<<4))/2  (pre-swizzled; k_main copies linearly)
    unsigned short* ai = Aimg + (size_t)tile * AIMG_SH_PER_TILE;
    #pragma unroll 1
    for (int rec = qtr * 1536 + tid; rec < (qtr + 1) * 1536; rec += 256) {
        int t = rec / 48;
        int s16 = (rec - t * 48) * 16;
        int j0 = (s16 ^ ((t & 7) << 4)) >> 1;
        __attribute__((aligned(16))) unsigned short hv[8];
        #pragma unroll
        for (int r = 0; r < 8; ++r) {
            int j = j0 + r;
            float v;
            if (j < 320) { int e5 = j / 5, k = j - e5 * 5; v = xwin[(t + k) * 65 + e5]; }
            else v = (j == 320) ? 1.0f : 0.f;
            hv[r] = f2bf(v);
        }
        *(short8*)(ai + t * 384 + (s16 >> 1)) = *(short8*)hv;
    }

    // DC[tile][rec*64+lane], rec = mfw*96 + nf*4 + r:
    //   d'[mfw*16+(lane>>4)*4+r][nf*16+(lane&15)]
    unsigned short* dc = DC + (size_t)tile * DC_SH_PER_TILE;
    #pragma unroll 1
    for (int g = qtr * 12288 + tid; g < (qtr + 1) * 12288; g += 256) {
        int lane = g & 63, rec = g >> 6;
        int r = rec & 3;
        int nf = (rec >> 2) % NFR;
        int mfw = rec / 96;
        int t = mfw * 16 + ((lane >> 4) << 2) + r;
        int i = nf * 16 + (lane & 15);
        float v;
        if (i < 320) { int e5 = i / 5, k = i - e5 * 5; v = xwin[(t + k) * 65 + e5]; }
        else v = (i == 320) ? 1.0f : 0.f;
        dc[g] = f2bf(v);
    }
}

// ---- k_main: block = (tile, e-pair). C = D' U_e, h = rowdot(C, D') ----
__global__ __launch_bounds__(1024, 1) void k_main(const unsigned short* __restrict__ Aimg,
                                                  const unsigned short* __restrict__ Mfrag,
                                                  const unsigned short* __restrict__ DC,
                                                  float* __restrict__ hbuf) {
    __shared__ unsigned short At[MT2 * (ATS / 2)];  // 96KB pre-swizzled image
    __shared__ float hpart[2][8][64];

    const int tid = threadIdx.x;
    const int bid = blockIdx.x;                 // 256 blocks = 1/CU
    const int tile = bid >> 5;
    const int ep = bid & 31;                    // XCD = ep%8
    const int e0 = ep * 2;
    const int tok0 = tile * MT2;

    {   // linear coalesced stage of the pre-swizzled A image
        const short8* src = (const short8*)(Aimg + (size_t)tile * AIMG_SH_PER_TILE);
        short8* dst = (short8*)At;
        #pragma unroll
        for (int k = 0; k < 6; ++k)
            dst[k * 1024 + tid] = src[k * 1024 + tid];
    }
    __syncthreads();

    const int lane = tid & 63, wv = tid >> 6;   // 16 waves
    const int wm = wv >> 3;
    // balanced wn permutation: pairs (0,7),(1,6),(2,5),(3,4) share a SIMD
    const int w3 = wv & 3;
    const int wn = (wv & 4) ? (7 - w3) : w3;
    const int nf0 = wn * 3;
    const int kc0 = (3 * wn) >> 1;              // triangular skip start
    const int arow = wm * 64 + (lane & 15);
    const int aslot = (lane >> 4) << 4;
    char* Atb = (char*)At;

    #pragma unroll 1
    for (int eo = 0; eo < 2; ++eo) {
        const unsigned short* Bbase = Mfrag + (size_t)(e0 + eo) * (KPAD * NPAD);

        f32x4 acc[4][3];
        #pragma unroll
        for (int mf = 0; mf < 4; ++mf)
            #pragma unroll
            for (int q = 0; q < 3; ++q) acc[mf][q] = f32x4{0.f,0.f,0.f,0.f};

        short8 B0[3], B1[3];

#define BLD(DST, KCV)                                                              \
    do { if ((KCV) < KCHK) {                                                       \
        _Pragma("unroll")                                                          \
        for (int q = 0; q < 3; ++q)                                                \
            DST[q] = *(const short8*)(Bbase +                                      \
                ((size_t)(((KCV) * NFR + nf0 + q) * 64 + lane)) * 8);              \
    } } while (0)

#define STEP(KCV, CUR)                                                             \
    do {                                                                           \
        short8 Af[4];                                                              \
        _Pragma("unroll")                                                          \
        for (int mf = 0; mf < 4; ++mf) {                                           \
            int t = arow + mf * 16;                                                \
            int jb = (KCV) * 64 + aslot;                                           \
            Af[mf] = *(const short8*)(Atb + t * ATS + (jb ^ ((t & 7) << 4)));      \
        }                                                                          \
        __builtin_amdgcn_s_setprio(1);                                             \
        _Pragma("unroll")                                                          \
        for (int mf = 0; mf < 4; ++mf) {                                           \
            _Pragma("unroll")                                                      \
            for (int q = 0; q < 3; ++q)                                            \
                acc[mf][q] = __builtin_amdgcn_mfma_f32_16x16x32_bf16(              \
                    Af[mf], CUR[q], acc[mf][q], 0, 0, 0);                          \
        }                                                                          \
        __builtin_amdgcn_s_setprio(0);                                             \
    } while (0)

        BLD(B0, kc0);
        BLD(B1, kc0 + 1);
        int kc = kc0;
        #pragma unroll 1
        for (; kc + 1 < KCHK; kc += 2) {
            STEP(kc, B0);
            BLD(B0, kc + 2);
            STEP(kc + 1, B1);
            BLD(B1, kc + 3);
        }
        if (kc < KCHK) STEP(kc, B0);
#undef STEP
#undef BLD

        // contraction: s[mf][r] = sum_i C[t][i]*d'[t][i]; d' from DC (coalesced)
        float s[4][4];
        #pragma unroll
        for (int mf = 0; mf < 4; ++mf)
            #pragma unroll
            for (int r = 0; r < 4; ++r) s[mf][r] = 0.f;

        const unsigned short* DCb = DC + (size_t)tile * DC_SH_PER_TILE + lane;
        #pragma unroll
        for (int q = 0; q < 3; ++q) {
            #pragma unroll
            for (int mf = 0; mf < 4; ++mf)
                #pragma unroll
                for (int r = 0; r < 4; ++r) {
                    unsigned short dv =
                        DCb[((wm * 4 + mf) * 96 + (nf0 + q) * 4 + r) * 64];
                    s[mf][r] += acc[mf][q][r] * bf2f(dv);
                }
        }
        #pragma unroll
        for (int mf = 0; mf < 4; ++mf)
            #pragma unroll
            for (int r = 0; r < 4; ++r) {
                float v = s[mf][r];
                v += __shfl_xor(v, 1);
                v += __shfl_xor(v, 2);
                v += __shfl_xor(v, 4);
                v += __shfl_xor(v, 8);
                s[mf][r] = v;
            }
        if ((lane & 15) == 0) {
            #pragma unroll
            for (int mf = 0; mf < 4; ++mf)
                #pragma unroll
                for (int r = 0; r < 4; ++r)
                    hpart[wm][wn][mf * 16 + ((lane >> 4) << 2) + r] = s[mf][r];
        }
        __syncthreads();
        if (tid < 128) {
            int wmx = tid >> 6, tl = tid & 63;
            float v = 0.f;
            #pragma unroll
            for (int w = 0; w < 8; ++w) v += hpart[wmx][w][tl];
            hbuf[(size_t)(tok0 + wmx * 64 + tl) * 64 + (e0 + eo)] = v;
        }
        __syncthreads();   // hpart reused next eo
    }
}

// ---- epilogue: out = GELU(hbuf + b1) @ W2 + b2 ----
__global__ void k_epi(const float* __restrict__ hbuf, const float* __restrict__ b1,
                      const float* __restrict__ W2, const float* __restrict__ b2,
                      float* __restrict__ out) {
    __shared__ float h[4 * 64];
    int tid = threadIdx.x;
    int t = tid >> 6, e = tid & 63;
    int token = blockIdx.x * 4 + t;
    float pre = hbuf[token * 64 + e] + b1[e];
    float hv = 0.5f * pre * (1.0f + erff(pre * 0.70710678118654752f));  // exact GELU
    h[t * 64 + e] = hv;
    __syncthreads();
    float s = b2[e];
    #pragma unroll 8
    for (int ee = 0; ee < 64; ++ee)
        s += h[t * 64 + ee] * W2[ee * 64 + e];
    out[token * 64 + e] = s;
}

extern "C" void kernel_launch(void* const* d_in, const int* in_sizes, int n_in,
                              void* d_out, int out_size, void* d_ws, size_t ws_size,
                              hipStream_t stream) {
    const float* x  = (const float*)d_in[0];
    const float* W1 = (const float*)d_in[1];
    const float* b1 = (const float*)d_in[2];
    const float* W2 = (const float*)d_in[3];
    const float* b2 = (const float*)d_in[4];
    float* out = (float*)d_out;

    unsigned short* W1c   = (unsigned short*)d_ws;
    unsigned short* Mfrag = (unsigned short*)((char*)d_ws + W1C_BYTES);
    float* hbuf           = (float*)((char*)d_ws + HBUF_OFF);
    unsigned short* Aimg  = (unsigned short*)((char*)d_ws + AIMG_OFF);
    unsigned short* DC    = (unsigned short*)((char*)d_ws + DC_OFF);

    k_t<<<(NF + 63) / 64, 256, 0, stream>>>(W1, W1c);
    k_pack<<<4224, 256, 0, stream>>>(W1c, Mfrag);
    k_aprep<<<32, 256, 0, stream>>>(x, Aimg, DC);
    k_main<<<256, 1024, 0, stream>>>(Aimg, Mfrag, DC, hbuf);
    k_epi<<<256, 256, 0, stream>>>(hbuf, b1, W2, b2, out);
}